// Round 1
// baseline (675.573 us; speedup 1.0000x reference)
//
#include <hip/hip_runtime.h>
#include <hip/hip_bf16.h>
#include <cstdint>
#include <cstddef>

#define NROWS 32768
#define NCLS  1000
#define KP    1024   // padded class dim

typedef unsigned short u16;
typedef __bf16 bf16x8 __attribute__((ext_vector_type(8)));
typedef float  f32x4  __attribute__((ext_vector_type(4)));

__device__ __forceinline__ void gld_lds16(const u16* g, u16* l) {
  __builtin_amdgcn_global_load_lds(
      (const __attribute__((address_space(1))) unsigned int*)g,
      (__attribute__((address_space(3))) unsigned int*)l, 16, 0, 0);
}

// ---- prep: bank f32 [1000x1000] -> bf16 M [1024x1024] and M^T [1024x1024], zero-padded
__global__ void prep_bank(const float* __restrict__ bank,
                          __hip_bfloat16* __restrict__ Mb,
                          __hip_bfloat16* __restrict__ MTb) {
  __shared__ float tile[32][33];
  const int bx = blockIdx.x * 32;  // k
  const int by = blockIdx.y * 32;  // j
  for (int t = threadIdx.y; t < 32; t += 8) {
    int j = by + t, k = bx + threadIdx.x;
    float v = (j < NCLS && k < NCLS) ? bank[j * NCLS + k] : 0.0f;
    Mb[j * KP + k] = __float2bfloat16(v);
    tile[t][threadIdx.x] = v;
  }
  __syncthreads();
  for (int t = threadIdx.y; t < 32; t += 8) {
    int k = bx + t, j = by + threadIdx.x;
    MTb[k * KP + j] = __float2bfloat16(tile[threadIdx.x][t]);
  }
}

// ---- fused: p_tar -> bf16 A (padded), argmax(p_tar), argmax(p_vlm), agreement atomics
__global__ __launch_bounds__(256)
void rows_kernel(const float* __restrict__ p_tar, const float* __restrict__ p_vlm,
                 __hip_bfloat16* __restrict__ Abf,
                 float* __restrict__ sums, float* __restrict__ counts) {
  const int wid  = threadIdx.x >> 6;
  const int lane = threadIdx.x & 63;
  const int row  = blockIdx.x * 4 + wid;
  const float* tr = p_tar + (size_t)row * NCLS;
  const float* vr = p_vlm + (size_t)row * NCLS;
  __hip_bfloat16* ar = Abf + (size_t)row * KP;

  float bvT = -1.0f; int biT = 0;
  for (int c = lane; c < NCLS; c += 64) {
    float v = tr[c];
    ar[c] = __float2bfloat16(v);
    if (v > bvT) { bvT = v; biT = c; }
  }
  if (lane < KP - NCLS) ar[NCLS + lane] = __float2bfloat16(0.0f);

  float bvV = -1.0f; int biV = 0;
  for (int c = lane; c < NCLS; c += 64) {
    float v = vr[c];
    if (v > bvV) { bvV = v; biV = c; }
  }
  // butterfly argmax reduce (first-occurrence semantics: prefer lower index on tie)
  #pragma unroll
  for (int d = 1; d < 64; d <<= 1) {
    float ov = __shfl_xor(bvT, d); int oi = __shfl_xor(biT, d);
    if (ov > bvT || (ov == bvT && oi < biT)) { bvT = ov; biT = oi; }
    float ov2 = __shfl_xor(bvV, d); int oi2 = __shfl_xor(biV, d);
    if (ov2 > bvV || (ov2 == bvV && oi2 < biV)) { bvV = ov2; biV = oi2; }
  }
  if (biT == biV) {                 // wave-uniform after reduction
    if (lane == 0) atomicAdd(&counts[biT], 1.0f);
    for (int c = lane; c < NCLS; c += 64)
      atomicAdd(&sums[(size_t)biT * NCLS + c], tr[c]);
  }
}

// ---- m97-style 128x128 bf16 MFMA GEMM, C = A @ Brows^T, K=1024
// WHICH==1: epilogue E = exp(norm*S) (masked col>=1000 -> 0), bf16 out
// WHICH==2: epilogue p_mix = mix(acc/rowsum, p_vlm), f32 out
template <int WHICH>
__global__ __launch_bounds__(256)
void gemm_bt(const u16* __restrict__ Amat, const u16* __restrict__ Bmat,
             __hip_bfloat16* __restrict__ Eout,
             const float* __restrict__ rowsum,
             const float* __restrict__ p_vlm,
             float* __restrict__ mix_out) {
  __shared__ u16 As[128 * 32];
  __shared__ u16 Bs[128 * 32];
  const int tid  = threadIdx.x;
  const int wid  = tid >> 6;
  const int lane = tid & 63;
  const int lr   = lane & 15;
  const int q    = lane >> 4;
  const int bm   = blockIdx.y;
  const int bn   = blockIdx.x;
  const int wm   = wid >> 1;
  const int wn   = wid & 1;

  f32x4 acc[4][4] = {};

  // staging: 8 wave-calls of 1024B cover each 8KB tile; this wave's two chunks
  const int srow = wid * 32 + (lane >> 2);   // tile row for chunk 0
  const int skb  = (lane & 3) * 8;           // k halfword offset
  const u16* ag0 = Amat + (size_t)(bm * 128 + srow) * KP + skb;
  const u16* ag1 = ag0 + (size_t)16 * KP;
  const u16* bg0 = Bmat + (size_t)(bn * 128 + srow) * KP + skb;
  const u16* bg1 = bg0 + (size_t)16 * KP;
  u16* as0 = &As[(wid * 2 + 0) * 512];
  u16* as1 = &As[(wid * 2 + 1) * 512];
  u16* bs0 = &Bs[(wid * 2 + 0) * 512];
  u16* bs1 = &Bs[(wid * 2 + 1) * 512];

  for (int k0 = 0; k0 < KP; k0 += 32) {
    gld_lds16(ag0 + k0, as0);
    gld_lds16(ag1 + k0, as1);
    gld_lds16(bg0 + k0, bs0);
    gld_lds16(bg1 + k0, bs1);
    __syncthreads();   // compiler emits vmcnt(0) drain before s_barrier

    bf16x8 af[4], bfr[4];
    #pragma unroll
    for (int t = 0; t < 4; ++t) {
      af[t]  = *(const bf16x8*)(&As[(wm * 64 + t * 16 + lr) * 32 + q * 8]);
      bfr[t] = *(const bf16x8*)(&Bs[(wn * 64 + t * 16 + lr) * 32 + q * 8]);
    }
    #pragma unroll
    for (int mt = 0; mt < 4; ++mt)
      #pragma unroll
      for (int nt = 0; nt < 4; ++nt)
        acc[mt][nt] = __builtin_amdgcn_mfma_f32_16x16x32_bf16(af[mt], bfr[nt], acc[mt][nt], 0, 0, 0);
    __syncthreads();
  }

  const float NORM = 0.03162277660168379f;  // 1/sqrt(1000)
  #pragma unroll
  for (int mt = 0; mt < 4; ++mt) {
    #pragma unroll
    for (int r = 0; r < 4; ++r) {
      const int gm = bm * 128 + wm * 64 + mt * 16 + q * 4 + r;
      if (WHICH == 1) {
        #pragma unroll
        for (int nt = 0; nt < 4; ++nt) {
          const int gn = bn * 128 + wn * 64 + nt * 16 + lr;
          float e = (gn < NCLS) ? __expf(acc[mt][nt][r] * NORM) : 0.0f;
          Eout[(size_t)gm * KP + gn] = __float2bfloat16(e);
        }
      } else {
        const float inv = 1.0f / rowsum[gm];
        #pragma unroll
        for (int nt = 0; nt < 4; ++nt) {
          const int gn = bn * 128 + wn * 64 + nt * 16 + lr;
          if (gn < NCLS) {
            float pt = acc[mt][nt][r] * inv;                 // p_tar_new
            float pv = p_vlm[(size_t)gm * NCLS + gn];
            float et = __expf(pt * __logf(pt + 1e-6f));      // exp(-u(pt))
            float ev = __expf(pv * __logf(pv + 1e-6f));
            mix_out[(size_t)gm * NCLS + gn] = (et * pt + ev * pv) / (et + ev);
          }
        }
      }
    }
  }
}

// ---- rowsum of E (bf16, padded cols are 0)
__global__ __launch_bounds__(256)
void rowsum_kernel(const u16* __restrict__ E, float* __restrict__ rs) {
  const int wid  = threadIdx.x >> 6;
  const int lane = threadIdx.x & 63;
  const int row  = blockIdx.x * 4 + wid;
  const u16* er = E + (size_t)row * KP;
  const bf16x8* p = (const bf16x8*)(er + lane * 16);
  bf16x8 v0 = p[0], v1 = p[1];
  float s = 0.0f;
  #pragma unroll
  for (int i = 0; i < 8; ++i) s += (float)v0[i] + (float)v1[i];
  #pragma unroll
  for (int d = 1; d < 64; d <<= 1) s += __shfl_xor(s, d);
  if (lane == 0) rs[row] = s;
}

// ---- bank EMA update
__global__ __launch_bounds__(256)
void bank_update(const float* __restrict__ bank, const float* __restrict__ sums,
                 const float* __restrict__ counts, const float* __restrict__ alpha,
                 float* __restrict__ out) {
  const int idx = blockIdx.x * 256 + threadIdx.x;
  if (idx >= NCLS * NCLS) return;
  const int r = idx / NCLS;
  const float cnt = counts[r];
  const float bv  = bank[idx];
  const float a   = alpha[0];
  out[idx] = (cnt > 0.0f) ? a * bv + (1.0f - a) * (sums[idx] / cnt) : bv;
}

extern "C" void kernel_launch(void* const* d_in, const int* in_sizes, int n_in,
                              void* d_out, int out_size, void* d_ws, size_t ws_size,
                              hipStream_t stream) {
  const float* p_tar = (const float*)d_in[0];
  const float* p_vlm = (const float*)d_in[1];
  const float* alpha = (const float*)d_in[2];
  const float* bank  = (const float*)d_in[3];
  float* out_mix  = (float*)d_out;                         // [32768*1000]
  float* out_bank = (float*)d_out + (size_t)NROWS * NCLS;  // [1000*1000]

  char* w = (char*)d_ws;
  __hip_bfloat16* Abf = (__hip_bfloat16*)w; w += (size_t)NROWS * KP * 2;  // 64 MB
  __hip_bfloat16* Ebf = (__hip_bfloat16*)w; w += (size_t)NROWS * KP * 2;  // 64 MB
  __hip_bfloat16* Mb  = (__hip_bfloat16*)w; w += (size_t)KP * KP * 2;     // 2 MB
  __hip_bfloat16* MTb = (__hip_bfloat16*)w; w += (size_t)KP * KP * 2;     // 2 MB
  float* sums   = (float*)w;                w += (size_t)NCLS * NCLS * 4; // 4 MB
  float* counts = (float*)w;                w += 1024 * 4;
  float* rs     = (float*)w;                w += (size_t)NROWS * 4;

  // zero the atomic accumulators (sums + counts are contiguous)
  hipMemsetAsync(sums, 0, (size_t)NCLS * NCLS * 4 + 1024 * 4, stream);

  prep_bank<<<dim3(KP / 32, KP / 32), dim3(32, 8), 0, stream>>>(bank, Mb, MTb);
  rows_kernel<<<NROWS / 4, 256, 0, stream>>>(p_tar, p_vlm, Abf, sums, counts);
  gemm_bt<1><<<dim3(KP / 128, NROWS / 128), 256, 0, stream>>>(
      (const u16*)Abf, (const u16*)Mb, Ebf, nullptr, nullptr, nullptr);
  rowsum_kernel<<<NROWS / 4, 256, 0, stream>>>((const u16*)Ebf, rs);
  gemm_bt<2><<<dim3(KP / 128, NROWS / 128), 256, 0, stream>>>(
      (const u16*)Ebf, (const u16*)MTb, nullptr, rs, p_vlm, out_mix);
  bank_update<<<(NCLS * NCLS + 255) / 256, 256, 0, stream>>>(bank, sums, counts, alpha, out_bank);
}

// Round 2
// 603.897 us; speedup vs baseline: 1.1187x; 1.1187x over previous
//
#include <hip/hip_runtime.h>
#include <hip/hip_bf16.h>
#include <cstdint>
#include <cstddef>

#define NROWS 32768
#define NCLS  1000
#define KP    1024   // padded class dim

typedef unsigned short u16;
typedef __bf16 bf16x8 __attribute__((ext_vector_type(8)));
typedef __bf16 bf16x4 __attribute__((ext_vector_type(4)));
typedef float  f32x4  __attribute__((ext_vector_type(4)));

__device__ __forceinline__ void gld_lds16(const u16* g, u16* l) {
  __builtin_amdgcn_global_load_lds(
      (const __attribute__((address_space(1))) unsigned int*)g,
      (__attribute__((address_space(3))) unsigned int*)l, 16, 0, 0);
}

// ---- prep: bank f32 [1000x1000] -> bf16 M [1024x1024] and M^T [1024x1024], zero-padded
__global__ void prep_bank(const float* __restrict__ bank,
                          __hip_bfloat16* __restrict__ Mb,
                          __hip_bfloat16* __restrict__ MTb) {
  __shared__ float tile[32][33];
  const int bx = blockIdx.x * 32;  // k
  const int by = blockIdx.y * 32;  // j
  for (int t = threadIdx.y; t < 32; t += 8) {
    int j = by + t, k = bx + threadIdx.x;
    float v = (j < NCLS && k < NCLS) ? bank[j * NCLS + k] : 0.0f;
    Mb[j * KP + k] = __float2bfloat16(v);
    tile[t][threadIdx.x] = v;
  }
  __syncthreads();
  for (int t = threadIdx.y; t < 32; t += 8) {
    int k = bx + t, j = by + threadIdx.x;
    MTb[k * KP + j] = __float2bfloat16(tile[threadIdx.x][t]);
  }
}

// ---- fused: p_tar -> bf16 A (padded), argmax(p_tar), argmax(p_vlm), agreement atomics
__global__ __launch_bounds__(256)
void rows_kernel(const float* __restrict__ p_tar, const float* __restrict__ p_vlm,
                 __hip_bfloat16* __restrict__ Abf,
                 float* __restrict__ sums, float* __restrict__ counts) {
  const int wid  = threadIdx.x >> 6;
  const int lane = threadIdx.x & 63;
  const int row  = blockIdx.x * 4 + wid;
  const float* tr = p_tar + (size_t)row * NCLS;
  const float* vr = p_vlm + (size_t)row * NCLS;
  const float4* tr4 = (const float4*)tr;
  const float4* vr4 = (const float4*)vr;
  __hip_bfloat16* ar = Abf + (size_t)row * KP;

  float bvT = -1.0f; int biT = 0;
  for (int i = lane; i < 250; i += 64) {   // 250 float4 per row
    float4 v = tr4[i];
    bf16x4 o;
    o[0] = (__bf16)v.x; o[1] = (__bf16)v.y; o[2] = (__bf16)v.z; o[3] = (__bf16)v.w;
    ((bf16x4*)ar)[i] = o;
    if (v.x > bvT) { bvT = v.x; biT = 4 * i; }
    if (v.y > bvT) { bvT = v.y; biT = 4 * i + 1; }
    if (v.z > bvT) { bvT = v.z; biT = 4 * i + 2; }
    if (v.w > bvT) { bvT = v.w; biT = 4 * i + 3; }
  }
  if (lane < KP - NCLS) ar[NCLS + lane] = __float2bfloat16(0.0f);

  float bvV = -1.0f; int biV = 0;
  for (int i = lane; i < 250; i += 64) {
    float4 v = vr4[i];
    if (v.x > bvV) { bvV = v.x; biV = 4 * i; }
    if (v.y > bvV) { bvV = v.y; biV = 4 * i + 1; }
    if (v.z > bvV) { bvV = v.z; biV = 4 * i + 2; }
    if (v.w > bvV) { bvV = v.w; biV = 4 * i + 3; }
  }
  // butterfly argmax reduce (first-occurrence: prefer lower index on tie)
  #pragma unroll
  for (int d = 1; d < 64; d <<= 1) {
    float ov = __shfl_xor(bvT, d); int oi = __shfl_xor(biT, d);
    if (ov > bvT || (ov == bvT && oi < biT)) { bvT = ov; biT = oi; }
    float ov2 = __shfl_xor(bvV, d); int oi2 = __shfl_xor(biV, d);
    if (ov2 > bvV || (ov2 == bvV && oi2 < biV)) { bvV = ov2; biV = oi2; }
  }
  if (biT == biV) {                 // wave-uniform after reduction
    if (lane == 0) atomicAdd(&counts[biT], 1.0f);
    for (int c = lane; c < NCLS; c += 64)
      atomicAdd(&sums[(size_t)biT * NCLS + c], tr[c]);
  }
}

// ---- pipelined 128x128 bf16 MFMA GEMM, C = A @ Brow^T, K=1024, dbuf prefetch
// WHICH==1: epilogue E = exp(norm*S) (cols>=1000 -> 0), bf16 out + atomic rowsum
// WHICH==2: epilogue p_mix = mix(acc/rowsum, p_vlm), f32 out
template <int WHICH>
__global__ __launch_bounds__(256, 4)
void gemm_bt(const u16* __restrict__ Amat, const u16* __restrict__ Bmat,
             __hip_bfloat16* __restrict__ Eout,
             float* __restrict__ rowsum,
             const float* __restrict__ p_vlm,
             float* __restrict__ mix_out) {
  __shared__ u16 As[2][128 * 32];
  __shared__ u16 Bs[2][128 * 32];
  const int tid  = threadIdx.x;
  const int wid  = tid >> 6;
  const int lane = tid & 63;
  const int lr   = lane & 15;
  const int q    = lane >> 4;
  // XCD swizzle: 8 n-blocks sharing one A-tile get linear ids == bm (mod 256)
  // -> same id mod 8 -> same XCD L2 (round-robin dispatch)
  const int L  = blockIdx.y * 8 + blockIdx.x;  // 0..2047
  const int bm = L & 255;
  const int bn = L >> 8;
  const int wm = wid >> 1;
  const int wn = wid & 1;

  f32x4 acc[4][4] = {};

  const int srow = wid * 32 + (lane >> 2);   // tile row for chunk 0
  const int skb  = (lane & 3) * 8;           // k halfword offset
  const u16* ag0 = Amat + (size_t)(bm * 128 + srow) * KP + skb;
  const u16* ag1 = ag0 + (size_t)16 * KP;
  const u16* bg0 = Bmat + (size_t)(bn * 128 + srow) * KP + skb;
  const u16* bg1 = bg0 + (size_t)16 * KP;
  const int lofs0 = (wid * 2 + 0) * 512;     // halfword offset inside buffer
  const int lofs1 = (wid * 2 + 1) * 512;

  // prologue: fill buffer 0
  gld_lds16(ag0, &As[0][lofs0]);
  gld_lds16(ag1, &As[0][lofs1]);
  gld_lds16(bg0, &Bs[0][lofs0]);
  gld_lds16(bg1, &Bs[0][lofs1]);

  const int NITER = KP / 32;  // 32
  for (int i = 0; i < NITER; ++i) {
    const int cur = i & 1;
    __syncthreads();  // vmcnt(0) drain publishes buf[cur]; all reads of buf[cur^1] done
    if (i + 1 < NITER) {
      const int k0 = (i + 1) * 32;
      const int nxt = cur ^ 1;
      gld_lds16(ag0 + k0, &As[nxt][lofs0]);
      gld_lds16(ag1 + k0, &As[nxt][lofs1]);
      gld_lds16(bg0 + k0, &Bs[nxt][lofs0]);
      gld_lds16(bg1 + k0, &Bs[nxt][lofs1]);
    }
    bf16x8 af[4], bfr[4];
    #pragma unroll
    for (int t = 0; t < 4; ++t) {
      af[t]  = *(const bf16x8*)(&As[cur][(wm * 64 + t * 16 + lr) * 32 + q * 8]);
      bfr[t] = *(const bf16x8*)(&Bs[cur][(wn * 64 + t * 16 + lr) * 32 + q * 8]);
    }
    #pragma unroll
    for (int mt = 0; mt < 4; ++mt)
      #pragma unroll
      for (int nt = 0; nt < 4; ++nt)
        acc[mt][nt] = __builtin_amdgcn_mfma_f32_16x16x32_bf16(af[mt], bfr[nt], acc[mt][nt], 0, 0, 0);
  }

  const float NORM = 0.03162277660168379f;  // 1/sqrt(1000)
  #pragma unroll
  for (int mt = 0; mt < 4; ++mt) {
    #pragma unroll
    for (int r = 0; r < 4; ++r) {
      const int gm = bm * 128 + wm * 64 + mt * 16 + q * 4 + r;
      if (WHICH == 1) {
        float psum = 0.0f;
        #pragma unroll
        for (int nt = 0; nt < 4; ++nt) {
          const int gn = bn * 128 + wn * 64 + nt * 16 + lr;
          float e = (gn < NCLS) ? __expf(acc[mt][nt][r] * NORM) : 0.0f;
          Eout[(size_t)gm * KP + gn] = __float2bfloat16(e);
          psum += e;
        }
        // reduce across the 16 lanes (same q -> same gm)
        psum += __shfl_xor(psum, 1);
        psum += __shfl_xor(psum, 2);
        psum += __shfl_xor(psum, 4);
        psum += __shfl_xor(psum, 8);
        if (lr == 0) atomicAdd(&rowsum[gm], psum);
      } else {
        const float inv = 1.0f / rowsum[gm];
        #pragma unroll
        for (int nt = 0; nt < 4; ++nt) {
          const int gn = bn * 128 + wn * 64 + nt * 16 + lr;
          if (gn < NCLS) {
            float pt = acc[mt][nt][r] * inv;                 // p_tar_new
            float pv = p_vlm[(size_t)gm * NCLS + gn];
            float et = __expf(pt * __logf(pt + 1e-6f));      // exp(-u(pt))
            float ev = __expf(pv * __logf(pv + 1e-6f));
            mix_out[(size_t)gm * NCLS + gn] = (et * pt + ev * pv) / (et + ev);
          }
        }
      }
    }
  }
}

// ---- bank EMA update
__global__ __launch_bounds__(256)
void bank_update(const float* __restrict__ bank, const float* __restrict__ sums,
                 const float* __restrict__ counts, const float* __restrict__ alpha,
                 float* __restrict__ out) {
  const int idx = blockIdx.x * 256 + threadIdx.x;
  if (idx >= NCLS * NCLS) return;
  const int r = idx / NCLS;
  const float cnt = counts[r];
  const float bv  = bank[idx];
  const float a   = alpha[0];
  out[idx] = (cnt > 0.0f) ? a * bv + (1.0f - a) * (sums[idx] / cnt) : bv;
}

extern "C" void kernel_launch(void* const* d_in, const int* in_sizes, int n_in,
                              void* d_out, int out_size, void* d_ws, size_t ws_size,
                              hipStream_t stream) {
  const float* p_tar = (const float*)d_in[0];
  const float* p_vlm = (const float*)d_in[1];
  const float* alpha = (const float*)d_in[2];
  const float* bank  = (const float*)d_in[3];
  float* out_mix  = (float*)d_out;                         // [32768*1000]
  float* out_bank = (float*)d_out + (size_t)NROWS * NCLS;  // [1000*1000]

  char* w = (char*)d_ws;
  __hip_bfloat16* Abf = (__hip_bfloat16*)w; w += (size_t)NROWS * KP * 2;  // 64 MB
  __hip_bfloat16* Ebf = (__hip_bfloat16*)w; w += (size_t)NROWS * KP * 2;  // 64 MB
  __hip_bfloat16* Mb  = (__hip_bfloat16*)w; w += (size_t)KP * KP * 2;     // 2 MB
  __hip_bfloat16* MTb = (__hip_bfloat16*)w; w += (size_t)KP * KP * 2;     // 2 MB
  float* sums   = (float*)w;                w += (size_t)NCLS * NCLS * 4; // 4 MB
  float* counts = (float*)w;                w += 1024 * 4;
  float* rs     = (float*)w;                w += (size_t)NROWS * 4;

  // zero atomic accumulators: sums + counts + rs are contiguous
  hipMemsetAsync(sums, 0, (size_t)NCLS * NCLS * 4 + 1024 * 4 + (size_t)NROWS * 4, stream);

  prep_bank<<<dim3(KP / 32, KP / 32), dim3(32, 8), 0, stream>>>(bank, Mb, MTb);
  rows_kernel<<<NROWS / 4, 256, 0, stream>>>(p_tar, p_vlm, Abf, sums, counts);
  gemm_bt<1><<<dim3(KP / 128, NROWS / 128), 256, 0, stream>>>(
      (const u16*)Abf, (const u16*)Mb, Ebf, rs, nullptr, nullptr);
  gemm_bt<2><<<dim3(KP / 128, NROWS / 128), 256, 0, stream>>>(
      (const u16*)Ebf, (const u16*)MTb, nullptr, rs, p_vlm, out_mix);
  bank_update<<<(NCLS * NCLS + 255) / 256, 256, 0, stream>>>(bank, sums, counts, alpha, out_bank);
}

// Round 3
// 597.416 us; speedup vs baseline: 1.1308x; 1.0108x over previous
//
#include <hip/hip_runtime.h>
#include <hip/hip_bf16.h>
#include <cstdint>
#include <cstddef>

#define NROWS 32768
#define NCLS  1000
#define KP    1024   // padded class dim
#define NCH   32     // k-chunks per panel (KP/32)

typedef unsigned short u16;
typedef __bf16 bf16x8 __attribute__((ext_vector_type(8)));
typedef float  f32x4  __attribute__((ext_vector_type(4)));

// Fragment-chunk layout ("X4"): matrix [Rows][KP] stored as
//   chunk(R, c) = 1KB block at ((R*NCH)+c)*512 halfwords, R = row/16, c = k/32
//   slot l (l=0..63, 16B) = elements [R*16 + (l&15)][c*32 + (l>>4)*8 + j], j=0..7
// => staging global loads, global_load_lds lane scatter, LDS fragment reads,
//    and MFMA A/B operand layout (m=lane&15, k=(lane>>4)*8+j) are ALL base+lane*16.

__device__ __forceinline__ void gld_lds16(const u16* g, u16* l) {
  __builtin_amdgcn_global_load_lds(
      (const __attribute__((address_space(1))) unsigned int*)g,
      (__attribute__((address_space(3))) unsigned int*)l, 16, 0, 0);
}

// ---- prep: bank f32 [1000x1000] -> M4 and MT4 (fragment-chunk, zero-padded to 1024)
__global__ __launch_bounds__(128)
void prep4_bank(const float* __restrict__ bank,
                __hip_bfloat16* __restrict__ M4,
                __hip_bfloat16* __restrict__ MT4) {
  __shared__ float tile[32][33];
  const int tx = blockIdx.x;  // col chunk (k)
  const int ty = blockIdx.y;  // row chunk (j)
  const int t  = threadIdx.x;
  {
    const int r = t >> 2, c0 = (t & 3) * 8;
    const int gj = ty * 32 + r;
    #pragma unroll
    for (int j = 0; j < 8; ++j) {
      const int gk = tx * 32 + c0 + j;
      tile[r][c0 + j] = (gj < NCLS && gk < NCLS) ? bank[gj * NCLS + gk] : 0.0f;
    }
  }
  __syncthreads();
  const int w = t >> 6, lane = t & 63, lr = lane & 15, qq = lane >> 4;
  if (w == 0) {
    #pragma unroll
    for (int s = 0; s < 2; ++s) {
      bf16x8 o;
      #pragma unroll
      for (int j = 0; j < 8; ++j) o[j] = (__bf16)tile[s * 16 + lr][qq * 8 + j];
      *(bf16x8*)((u16*)M4 + ((size_t)(ty * 2 + s) * NCH + tx) * 512 + lane * 8) = o;
    }
  } else {
    #pragma unroll
    for (int s = 0; s < 2; ++s) {
      bf16x8 o;
      #pragma unroll
      for (int j = 0; j < 8; ++j) o[j] = (__bf16)tile[qq * 8 + j][s * 16 + lr];
      *(bf16x8*)((u16*)MT4 + ((size_t)(tx * 2 + s) * NCH + ty) * 512 + lane * 8) = o;
    }
  }
}

// ---- fused: p_tar -> A4 (fragment-chunk bf16), argmax agreement + segment-sum atomics
// wave handles one 16-row panel; lane(q,lr): row lr, k = c*32 + q*8 + j
__global__ __launch_bounds__(256)
void rows4_kernel(const float* __restrict__ p_tar, const float* __restrict__ p_vlm,
                  __hip_bfloat16* __restrict__ A4,
                  float* __restrict__ sums, float* __restrict__ counts) {
  const int w = threadIdx.x >> 6, lane = threadIdx.x & 63;
  const int lr = lane & 15, q = lane >> 4;
  const int panel = blockIdx.x * 4 + w;          // 0..2047
  const int row   = panel * 16 + lr;
  const float* tr = p_tar + (size_t)row * NCLS;
  const float* vr = p_vlm + (size_t)row * NCLS;
  u16* a4 = (u16*)A4 + (size_t)panel * NCH * 512 + lane * 8;

  float bvT = -1.0f; int biT = 0;
  float bvV = -1.0f; int biV = 0;
  for (int c = 0; c < NCH; ++c) {
    const int k0 = c * 32 + q * 8;
    float v[8];
    if (k0 < NCLS) {
      float4 x = *(const float4*)(tr + k0);
      float4 y = *(const float4*)(tr + k0 + 4);
      v[0] = x.x; v[1] = x.y; v[2] = x.z; v[3] = x.w;
      v[4] = y.x; v[5] = y.y; v[6] = y.z; v[7] = y.w;
    } else {
      #pragma unroll
      for (int j = 0; j < 8; ++j) v[j] = 0.0f;
    }
    bf16x8 o;
    #pragma unroll
    for (int j = 0; j < 8; ++j) {
      o[j] = (__bf16)v[j];
      if (v[j] > bvT) { bvT = v[j]; biT = k0 + j; }
    }
    *(bf16x8*)(a4 + (size_t)c * 512) = o;
    if (k0 < NCLS) {
      float4 x = *(const float4*)(vr + k0);
      float4 y = *(const float4*)(vr + k0 + 4);
      float u[8] = {x.x, x.y, x.z, x.w, y.x, y.y, y.z, y.w};
      #pragma unroll
      for (int j = 0; j < 8; ++j)
        if (u[j] > bvV) { bvV = u[j]; biV = k0 + j; }
    }
  }
  // reduce across the 4 q-lanes owning row lr (xor 16, 32), first-occurrence ties
  #pragma unroll
  for (int d = 16; d < 64; d <<= 1) {
    float ov = __shfl_xor(bvT, d); int oi = __shfl_xor(biT, d);
    if (ov > bvT || (ov == bvT && oi < biT)) { bvT = ov; biT = oi; }
    float ov2 = __shfl_xor(bvV, d); int oi2 = __shfl_xor(biV, d);
    if (ov2 > bvV || (ov2 == bvV && oi2 < biV)) { bvV = ov2; biV = oi2; }
  }
  const int ag = (biT == biV) ? 1 : 0;
  for (int rr = 0; rr < 16; ++rr) {
    const int agr = __shfl(ag, rr);
    if (agr) {                                   // wave-uniform
      const int cls = __shfl(biT, rr);
      const float* trr = p_tar + (size_t)(panel * 16 + rr) * NCLS;
      for (int k = lane; k < NCLS; k += 64)
        atomicAdd(&sums[(size_t)cls * NCLS + k], trr[k]);
      if (lane == 0) atomicAdd(&counts[cls], 1.0f);
    }
  }
}

// ---- fragment-chunk MFMA GEMM, conflict-free LDS, dbuf, XCD swizzle
// WHICH==1: E4 = frag-chunk bf16 exp(norm*S) (cols>=1000 -> 0) + atomic rowsum
// WHICH==2: p_mix row-major f32
template <int WHICH>
__global__ __launch_bounds__(256, 4)
void gemm4(const u16* __restrict__ A4, const u16* __restrict__ B4,
           __hip_bfloat16* __restrict__ E4out, float* __restrict__ rowsum,
           const float* __restrict__ p_vlm, float* __restrict__ mix_out) {
  __shared__ u16 SH[4][4096];   // [0],[1]=A dbuf; [2],[3]=B dbuf; epilogue bounce
  const int tid  = threadIdx.x;
  const int w    = tid >> 6;
  const int lane = tid & 63;
  const int lr   = lane & 15;
  const int q    = lane >> 4;
  const int L    = blockIdx.y * 8 + blockIdx.x;   // 0..2047
  const int bm   = L & 255;                       // 8 sharers of A-tile -> same XCD
  const int bn   = L >> 8;
  const int wm   = w >> 1;
  const int wn   = w & 1;

  f32x4 acc[4][4] = {};

  // wave w stages A panels {2w,2w+1} and B panels {2w,2w+1} of the block's 8
  const u16* ga0 = A4 + ((size_t)(bm * 8 + 2 * w) * NCH) * 512 + lane * 8;
  const u16* ga1 = ga0 + (size_t)NCH * 512;
  const u16* gb0 = B4 + ((size_t)(bn * 8 + 2 * w) * NCH) * 512 + lane * 8;
  const u16* gb1 = gb0 + (size_t)NCH * 512;

  gld_lds16(ga0, &SH[0][(2 * w + 0) * 512]);
  gld_lds16(ga1, &SH[0][(2 * w + 1) * 512]);
  gld_lds16(gb0, &SH[2][(2 * w + 0) * 512]);
  gld_lds16(gb1, &SH[2][(2 * w + 1) * 512]);

  for (int i = 0; i < NCH; ++i) {
    const int cur = i & 1;
    __syncthreads();                     // publishes buf[cur]
    if (i + 1 < NCH) {
      const int nxt = cur ^ 1;
      const size_t ko = (size_t)(i + 1) * 512;
      gld_lds16(ga0 + ko, &SH[nxt][(2 * w + 0) * 512]);
      gld_lds16(ga1 + ko, &SH[nxt][(2 * w + 1) * 512]);
      gld_lds16(gb0 + ko, &SH[2 + nxt][(2 * w + 0) * 512]);
      gld_lds16(gb1 + ko, &SH[2 + nxt][(2 * w + 1) * 512]);
    }
    bf16x8 af[4], bfr[4];
    #pragma unroll
    for (int t = 0; t < 4; ++t) {
      af[t]  = *(const bf16x8*)(&SH[cur][(wm * 4 + t) * 512 + lane * 8]);
      bfr[t] = *(const bf16x8*)(&SH[2 + cur][(wn * 4 + t) * 512 + lane * 8]);
    }
    #pragma unroll
    for (int mt = 0; mt < 4; ++mt)
      #pragma unroll
      for (int nt = 0; nt < 4; ++nt)
        acc[mt][nt] = __builtin_amdgcn_mfma_f32_16x16x32_bf16(af[mt], bfr[nt], acc[mt][nt], 0, 0, 0);
  }

  const float NORM = 0.03162277660168379f;  // 1/sqrt(1000)
  if (WHICH == 1) {
    __syncthreads();                 // LDS now reusable for epilogue bounce
    u16* ep = &SH[w][0];             // 8KB per-wave private region
    #pragma unroll
    for (int mt = 0; mt < 4; ++mt) {
      float psum[4] = {0.f, 0.f, 0.f, 0.f};
      #pragma unroll
      for (int nt = 0; nt < 4; ++nt) {
        const int gn = bn * 128 + wn * 64 + nt * 16 + lr;
        const int cc = nt >> 1;                      // chunk within wave (0..1)
        const int q2 = (nt & 1) * 2 + (lr >> 3);     // k-subchunk in chunk
        const int jj = lr & 7;
        #pragma unroll
        for (int r = 0; r < 4; ++r) {
          float e = (gn < NCLS) ? __expf(acc[mt][nt][r] * NORM) : 0.0f;
          psum[r] += e;
          __hip_bfloat16 h = __float2bfloat16(e);
          ep[(mt * 2 + cc) * 512 + (q2 * 16 + q * 4 + r) * 8 + jj] = *(u16*)&h;
        }
      }
      #pragma unroll
      for (int r = 0; r < 4; ++r) {
        float s = psum[r];
        s += __shfl_xor(s, 1); s += __shfl_xor(s, 2);
        s += __shfl_xor(s, 4); s += __shfl_xor(s, 8);
        if (lr == 0) atomicAdd(&rowsum[bm * 128 + wm * 64 + mt * 16 + q * 4 + r], s);
      }
    }
    #pragma unroll
    for (int ch = 0; ch < 8; ++ch) {   // coalesced 1KB flushes
      const int mt = ch >> 1, cc = ch & 1;
      bf16x8 v = *(const bf16x8*)(&ep[ch * 512 + lane * 8]);
      const size_t Rg = bm * 8 + wm * 4 + mt;
      const size_t cg = bn * 4 + wn * 2 + cc;
      *(bf16x8*)((u16*)E4out + (Rg * NCH + cg) * 512 + lane * 8) = v;
    }
  } else {
    #pragma unroll
    for (int mt = 0; mt < 4; ++mt) {
      #pragma unroll
      for (int r = 0; r < 4; ++r) {
        const int gm = bm * 128 + wm * 64 + mt * 16 + q * 4 + r;
        const float inv = 1.0f / rowsum[gm];
        #pragma unroll
        for (int nt = 0; nt < 4; ++nt) {
          const int gn = bn * 128 + wn * 64 + nt * 16 + lr;
          if (gn < NCLS) {
            float pt = acc[mt][nt][r] * inv;                 // p_tar_new
            float pv = p_vlm[(size_t)gm * NCLS + gn];
            float et = __expf(pt * __logf(pt + 1e-6f));      // exp(-u(pt))
            float ev = __expf(pv * __logf(pv + 1e-6f));
            mix_out[(size_t)gm * NCLS + gn] = (et * pt + ev * pv) / (et + ev);
          }
        }
      }
    }
  }
}

// ---- bank EMA update
__global__ __launch_bounds__(256)
void bank_update(const float* __restrict__ bank, const float* __restrict__ sums,
                 const float* __restrict__ counts, const float* __restrict__ alpha,
                 float* __restrict__ out) {
  const int idx = blockIdx.x * 256 + threadIdx.x;
  if (idx >= NCLS * NCLS) return;
  const int r = idx / NCLS;
  const float cnt = counts[r];
  const float bv  = bank[idx];
  const float a   = alpha[0];
  out[idx] = (cnt > 0.0f) ? a * bv + (1.0f - a) * (sums[idx] / cnt) : bv;
}

extern "C" void kernel_launch(void* const* d_in, const int* in_sizes, int n_in,
                              void* d_out, int out_size, void* d_ws, size_t ws_size,
                              hipStream_t stream) {
  const float* p_tar = (const float*)d_in[0];
  const float* p_vlm = (const float*)d_in[1];
  const float* alpha = (const float*)d_in[2];
  const float* bank  = (const float*)d_in[3];
  float* out_mix  = (float*)d_out;                         // [32768*1000]
  float* out_bank = (float*)d_out + (size_t)NROWS * NCLS;  // [1000*1000]

  char* w = (char*)d_ws;
  __hip_bfloat16* A4  = (__hip_bfloat16*)w; w += (size_t)NROWS * KP * 2;  // 64 MB
  __hip_bfloat16* E4  = (__hip_bfloat16*)w; w += (size_t)NROWS * KP * 2;  // 64 MB
  __hip_bfloat16* M4  = (__hip_bfloat16*)w; w += (size_t)KP * KP * 2;     // 2 MB
  __hip_bfloat16* MT4 = (__hip_bfloat16*)w; w += (size_t)KP * KP * 2;     // 2 MB
  float* sums   = (float*)w;                w += (size_t)NCLS * NCLS * 4; // 4 MB
  float* counts = (float*)w;                w += 1024 * 4;
  float* rs     = (float*)w;                w += (size_t)NROWS * 4;

  // zero atomic accumulators: sums + counts + rs are contiguous
  hipMemsetAsync(sums, 0, (size_t)NCLS * NCLS * 4 + 1024 * 4 + (size_t)NROWS * 4, stream);

  prep4_bank<<<dim3(32, 32), 128, 0, stream>>>(bank, M4, MT4);
  rows4_kernel<<<NROWS / 64, 256, 0, stream>>>(p_tar, p_vlm, A4, sums, counts);
  gemm4<1><<<dim3(8, 256), 256, 0, stream>>>(
      (const u16*)A4, (const u16*)M4, E4, rs, nullptr, nullptr);
  gemm4<2><<<dim3(8, 256), 256, 0, stream>>>(
      (const u16*)E4, (const u16*)MT4, nullptr, rs, p_vlm, out_mix);
  bank_update<<<(NCLS * NCLS + 255) / 256, 256, 0, stream>>>(bank, sums, counts, alpha, out_bank);
}